// Round 3
// baseline (380.553 us; speedup 1.0000x reference)
//
#include <hip/hip_runtime.h>
#include <hip/hip_cooperative_groups.h>

namespace cg = cooperative_groups;

// Attention over channel dim: B=16, HW=16384, C=64, fp32.
// scores[b,q,k] = sum_hw Q[b,hw,q]*K[b,hw,k]; attn=softmax_k; out[b,hw,q]=sum_k attn[b,q,k]*V[b,hw,k]
//
// ws: partial scores [B][32][64][64] fp32 (8 MiB), then attn_t [B][64k][64q] fp32 (256 KB).
//
// Primary path: ONE cooperative kernel (512 blocks x 256 thr), phases separated
// by grid.sync() — removes two kernel-launch gaps. Fallback: the proven
// 3-kernel pipeline if hipLaunchCooperativeKernel refuses.

#define SPLITN 32
#define NT 16                    // (16384/32) rows / 32-row tiles

union LdsU {
  struct { float4 q[2][512]; float4 k[2][512]; } t;   // 32 KB: scores double-buffer
  float red[2][4096];                                 // 32 KB: cross-wave reduction
  struct { float4 v[128 * 17]; float4 a[64 * 16]; } c;// 50 KB: out-phase V(+pad) & attn
};

// ---------------- Phase A: partial scores (split-K GEMM, 8x8 register tile, double-buffered) ----------------
// 4 waves compute the SAME 64x64 (q,k) tile over disjoint row subsets
// (r = i*4 + w); T14 staging: issue next tile's global loads, compute, LDS-write,
// ONE barrier per iter. 2-step LDS tree reduction, coalesced store.
__device__ __forceinline__ void scores_phase(LdsU& lds,
    const float* __restrict__ Q, const float* __restrict__ K,
    float* __restrict__ partial, int bs, int tid) {
  const int b = bs >> 5;
  const int s = bs & 31;
  const int w = tid >> 6;
  const int l = tid & 63;
  const int q0 = (l >> 3) * 8;
  const int k0 = (l & 7) * 8;

  float acc[8][8];
#pragma unroll
  for (int i = 0; i < 8; ++i)
#pragma unroll
    for (int j = 0; j < 8; ++j) acc[i][j] = 0.f;

  const float4* Qg = (const float4*)(Q + ((size_t)b * 16384 + (size_t)s * 512) * 64);
  const float4* Kg = (const float4*)(K + ((size_t)b * 16384 + (size_t)s * 512) * 64);

  lds.t.q[0][tid]       = Qg[tid];
  lds.t.q[0][tid + 256] = Qg[tid + 256];
  lds.t.k[0][tid]       = Kg[tid];
  lds.t.k[0][tid + 256] = Kg[tid + 256];

  for (int t = 0; t < NT; ++t) {
    __syncthreads();
    const int cb = t & 1;

    float4 pq0, pq1, pk0, pk1;
    if (t + 1 < NT) {
      pq0 = Qg[(t + 1) * 512 + tid];
      pq1 = Qg[(t + 1) * 512 + tid + 256];
      pk0 = Kg[(t + 1) * 512 + tid];
      pk1 = Kg[(t + 1) * 512 + tid + 256];
    }

#pragma unroll
    for (int i = 0; i < 8; ++i) {
      const int r = (i << 2) + w;
      float4 qa = lds.t.q[cb][r * 16 + (q0 >> 2)];
      float4 qb = lds.t.q[cb][r * 16 + (q0 >> 2) + 1];
      float4 ka = lds.t.k[cb][r * 16 + (k0 >> 2)];
      float4 kb = lds.t.k[cb][r * 16 + (k0 >> 2) + 1];
      float qv[8] = {qa.x, qa.y, qa.z, qa.w, qb.x, qb.y, qb.z, qb.w};
      float kv[8] = {ka.x, ka.y, ka.z, ka.w, kb.x, kb.y, kb.z, kb.w};
#pragma unroll
      for (int ii = 0; ii < 8; ++ii)
#pragma unroll
        for (int jj = 0; jj < 8; ++jj)
          acc[ii][jj] += qv[ii] * kv[jj];
    }

    if (t + 1 < NT) {
      const int nb = (t + 1) & 1;
      lds.t.q[nb][tid]       = pq0;
      lds.t.q[nb][tid + 256] = pq1;
      lds.t.k[nb][tid]       = pk0;
      lds.t.k[nb][tid + 256] = pk1;
    }
  }

  __syncthreads();
  if (w >= 2) {
    float4* dst = (float4*)lds.red[w - 2];
#pragma unroll
    for (int i = 0; i < 8; ++i) {
      dst[(q0 + i) * 16 + (k0 >> 2)]     = make_float4(acc[i][0], acc[i][1], acc[i][2], acc[i][3]);
      dst[(q0 + i) * 16 + (k0 >> 2) + 1] = make_float4(acc[i][4], acc[i][5], acc[i][6], acc[i][7]);
    }
  }
  __syncthreads();
  if (w < 2) {
    float4* dst = (float4*)lds.red[w];
#pragma unroll
    for (int i = 0; i < 8; ++i) {
      float4 u = dst[(q0 + i) * 16 + (k0 >> 2)];
      float4 v = dst[(q0 + i) * 16 + (k0 >> 2) + 1];
      dst[(q0 + i) * 16 + (k0 >> 2)]     = make_float4(u.x + acc[i][0], u.y + acc[i][1], u.z + acc[i][2], u.w + acc[i][3]);
      dst[(q0 + i) * 16 + (k0 >> 2) + 1] = make_float4(v.x + acc[i][4], v.y + acc[i][5], v.z + acc[i][6], v.w + acc[i][7]);
    }
  }
  __syncthreads();
  float4* p4 = (float4*)(partial + (size_t)bs * 4096);
  const float4* r0 = (const float4*)lds.red[0];
  const float4* r1 = (const float4*)lds.red[1];
#pragma unroll
  for (int c = 0; c < 4; ++c) {
    float4 x = r0[c * 256 + tid];
    float4 y = r1[c * 256 + tid];
    p4[c * 256 + tid] = make_float4(x.x + y.x, x.y + y.y, x.z + y.z, x.w + y.w);
  }
}

// ---------------- Phase B: reduce partials + softmax, store TRANSPOSED attn_t[b][k][q] ----------------
// One wave per task (b, q-quad): lane = (ql 0..3, k4 0..15), float4 reads,
// 16-lane shuffle reduce per q row.
__device__ __forceinline__ void softmax_task(
    const float* __restrict__ partial, float* __restrict__ attn_t, int task, int l) {
  const int b = task >> 4;
  const int q0 = (task & 15) * 4;
  const int ql = l >> 4;
  const int k4 = l & 15;

  const float4* P = (const float4*)partial;
  float4 v = make_float4(0.f, 0.f, 0.f, 0.f);
  for (int s = 0; s < SPLITN; ++s) {
    float4 t = P[((size_t)(b * SPLITN + s) * 64 + q0 + ql) * 16 + k4];
    v.x += t.x; v.y += t.y; v.z += t.z; v.w += t.w;
  }

  float m = fmaxf(fmaxf(v.x, v.y), fmaxf(v.z, v.w));
#pragma unroll
  for (int off = 8; off > 0; off >>= 1)
    m = fmaxf(m, __shfl_xor(m, off, 64));
  float4 e = make_float4(__expf(v.x - m), __expf(v.y - m), __expf(v.z - m), __expf(v.w - m));
  float sum = e.x + e.y + e.z + e.w;
#pragma unroll
  for (int off = 8; off > 0; off >>= 1)
    sum += __shfl_xor(sum, off, 64);
  const float inv = 1.f / sum;

  float* A = attn_t + (size_t)b * 4096;
  A[(4 * k4 + 0) * 64 + q0 + ql] = e.x * inv;
  A[(4 * k4 + 1) * 64 + q0 + ql] = e.y * inv;
  A[(4 * k4 + 2) * 64 + q0 + ql] = e.z * inv;
  A[(4 * k4 + 3) * 64 + q0 + ql] = e.w * inv;
}

// ---------------- Phase C: out = V * attn_t (register-tiled, 8 rows x 4 q per thread) ----------------
// V in LDS padded to 68 floats/row (conflict-free); attn float4 over q (2-way,
// free). 12 ds_read_b128 per 128 FMAs, 32 independent accumulators, coalesced
// float4 stores. Caller must have lds.c.a loaded (load_attn_lds) and the LDS
// v-region free of pending readers.
__device__ __forceinline__ void load_attn_lds(LdsU& lds, const float* __restrict__ attn_t,
                                              int b, int tid) {
  const float4* Ag = (const float4*)(attn_t + (size_t)b * 4096);
#pragma unroll
  for (int u = 0; u < 4; ++u)
    lds.c.a[u * 256 + tid] = Ag[u * 256 + tid];
}

__device__ __forceinline__ void out_tile(LdsU& lds, const float* __restrict__ V,
                                         float* __restrict__ out, int b, int tile, int tid) {
  const int g = tid >> 4;
  const int qg = tid & 15;

  const float4* Vg = (const float4*)(V + ((size_t)b * 16384 + (size_t)tile * 128) * 64);
#pragma unroll
  for (int u = 0; u < 8; ++u) {
    const int idx = u * 256 + tid;
    lds.c.v[(idx >> 4) * 17 + (idx & 15)] = Vg[idx];
  }
  __syncthreads();                      // V (and A on first call) visible

  float acc[8][4];
#pragma unroll
  for (int i = 0; i < 8; ++i)
#pragma unroll
    for (int j = 0; j < 4; ++j) acc[i][j] = 0.f;

  for (int k4 = 0; k4 < 16; ++k4) {
    const float4 a0 = lds.c.a[(4 * k4 + 0) * 16 + qg];
    const float4 a1 = lds.c.a[(4 * k4 + 1) * 16 + qg];
    const float4 a2 = lds.c.a[(4 * k4 + 2) * 16 + qg];
    const float4 a3 = lds.c.a[(4 * k4 + 3) * 16 + qg];
#pragma unroll
    for (int i = 0; i < 8; ++i) {
      const float4 v = lds.c.v[(i * 16 + g) * 17 + k4];
      acc[i][0] += v.x * a0.x + v.y * a1.x + v.z * a2.x + v.w * a3.x;
      acc[i][1] += v.x * a0.y + v.y * a1.y + v.z * a2.y + v.w * a3.y;
      acc[i][2] += v.x * a0.z + v.y * a1.z + v.z * a2.z + v.w * a3.z;
      acc[i][3] += v.x * a0.w + v.y * a1.w + v.z * a2.w + v.w * a3.w;
    }
  }

  float4* og = (float4*)(out + ((size_t)b * 16384 + (size_t)tile * 128) * 64);
#pragma unroll
  for (int i = 0; i < 8; ++i) {
    const int row = i * 16 + g;
    og[row * 16 + qg] = make_float4(acc[i][0], acc[i][1], acc[i][2], acc[i][3]);
  }
}

// ---------------- Fused cooperative kernel: 512 blocks x 256 threads ----------------
__global__ __launch_bounds__(256, 3) void fused_kernel(
    const float* __restrict__ Q, const float* __restrict__ K,
    const float* __restrict__ V, float* __restrict__ out,
    float* __restrict__ partial, float* __restrict__ attn_t) {
  const int blk = blockIdx.x;           // 0..511 = b*32 + s
  const int tid = threadIdx.x;
  const int w = tid >> 6;
  const int l = tid & 63;

  __shared__ LdsU lds;                  // 50 KB -> 3 blocks/CU; grid 512 co-resident at 2/CU

  cg::grid_group grid = cg::this_grid();

  // Phase A: partial scores for split-chunk blk.
  scores_phase(lds, Q, K, partial, blk, tid);

  grid.sync();

  // Phase B: 256 softmax tasks on blocks 0..63 (one task per wave).
  if (blk < 64) softmax_task(partial, attn_t, (blk << 2) + w, l);

  grid.sync();

  // Phase C: 4 output tiles of 128 rows; b = blk>>5 constant, A loaded once.
  {
    const int b = blk >> 5;
    load_attn_lds(lds, attn_t, b, tid);
    for (int it = 0; it < 4; ++it) {
      if (it) __syncthreads();          // previous tile's LDS reads done
      out_tile(lds, V, out, b, ((blk & 31) << 2) + it, tid);
    }
  }
}

// ---------------- Fallback: proven 3-kernel pipeline ----------------
__global__ __launch_bounds__(256) void scores_kernel(
    const float* __restrict__ Q, const float* __restrict__ K,
    float* __restrict__ partial) {
  __shared__ LdsU lds;
  scores_phase(lds, Q, K, partial, blockIdx.x, threadIdx.x);
}

__global__ __launch_bounds__(64) void softmax_kernel(
    const float* __restrict__ partial, float* __restrict__ attn_t) {
  softmax_task(partial, attn_t, blockIdx.x, threadIdx.x);
}

__global__ __launch_bounds__(256) void out_kernel(
    const float* __restrict__ V, const float* __restrict__ attn_t,
    float* __restrict__ out) {
  __shared__ LdsU lds;
  const int b = blockIdx.x >> 7;
  load_attn_lds(lds, attn_t, b, threadIdx.x);
  out_tile(lds, V, out, b, blockIdx.x & 127, threadIdx.x);
}

extern "C" void kernel_launch(void* const* d_in, const int* in_sizes, int n_in,
                              void* d_out, int out_size, void* d_ws, size_t ws_size,
                              hipStream_t stream) {
  const float* Q = (const float*)d_in[0];
  const float* K = (const float*)d_in[1];
  const float* V = (const float*)d_in[2];
  float* out = (float*)d_out;

  float* partial = (float*)d_ws;                            // 16*32*4096 floats = 8 MiB
  float* attn_t = partial + (size_t)16 * SPLITN * 4096;     // 256 KB, [b][k][q]

  void* args[] = {(void*)&Q, (void*)&K, (void*)&V, (void*)&out,
                  (void*)&partial, (void*)&attn_t};
  hipError_t err = hipLaunchCooperativeKernel((const void*)fused_kernel,
                                              dim3(512), dim3(256), args, 0, stream);
  if (err != hipSuccess) {
    // cooperative launch unavailable: proven 3-kernel path
    scores_kernel<<<16 * SPLITN, 256, 0, stream>>>(Q, K, partial);
    softmax_kernel<<<16 * 16 /*tasks*/ * 1, 64, 0, stream>>>(partial, attn_t);
    out_kernel<<<16 * 128, 256, 0, stream>>>(V, attn_t, out);
  }
}

// Round 4
// 266.145 us; speedup vs baseline: 1.4299x; 1.4299x over previous
//
#include <hip/hip_runtime.h>

// Attention over channel dim: B=16, HW=16384, C=64, fp32.
// scores[b,q,k] = sum_hw Q[b,hw,q]*K[b,hw,k]; attn=softmax_k; out[b,hw,q]=sum_k attn[b,q,k]*V[b,hw,k]
//
// ws: partial scores [B][SPLIT][64][64] fp32, then attn_t [B][64k][64q] fp32 (256 KB).
// SPLIT=64 (16 MiB) if ws allows, else 32 (8 MiB).
//
// Key structural fact exploited by kernels A and C: every staged row was
// consumed by exactly ONE wave (8- or 16-lane broadcast within the wave), so
// LDS staging of Q/K/V was pure overhead. Operands stream directly from
// global (L1 merges the lane-broadcast segments); LDS is used only where
// there is genuine cross-wave reuse (score reduction, attn tile).

// ---------------- Kernel A: partial scores, NO LDS staging, no main-loop barriers ----------------
// 4 waves, disjoint row subsets (r = 4t + w). Lane (q0,k0) 8x8 register tile.
// Per row: 4 global float4 loads (8 distinct 16B segs each, full row via L1)
// + 64 FMAs. One-row-ahead prefetch. Cross-wave LDS tree reduction at the end.
template <int SPLIT>
__global__ __launch_bounds__(256) void scores_kernel(
    const float* __restrict__ Q, const float* __restrict__ K,
    float* __restrict__ partial) {
  constexpr int CH = 16384 / SPLIT;       // rows per split chunk
  constexpr int NI = CH / 4;              // rows per wave
  const int bs = blockIdx.x;              // b * SPLIT + s
  const int b = bs / SPLIT;
  const int s = bs % SPLIT;
  const int tid = threadIdx.x;
  const int w = tid >> 6;                 // wave 0..3
  const int l = tid & 63;
  const int q0 = (l >> 3) * 8;            // 8 q per lane
  const int k0 = (l & 7) * 8;             // 8 k per lane

  __shared__ float red[2][4096];          // 32 KB: cross-wave reduction only

  float acc[8][8];
#pragma unroll
  for (int i = 0; i < 8; ++i)
#pragma unroll
    for (int j = 0; j < 8; ++j) acc[i][j] = 0.f;

  const float4* Qg = (const float4*)(Q + ((size_t)b * 16384 + (size_t)s * CH) * 64);
  const float4* Kg = (const float4*)(K + ((size_t)b * 16384 + (size_t)s * CH) * 64);

  int r = w;
  float4 qa = Qg[r * 16 + (q0 >> 2)];
  float4 qb = Qg[r * 16 + (q0 >> 2) + 1];
  float4 ka = Kg[r * 16 + (k0 >> 2)];
  float4 kb = Kg[r * 16 + (k0 >> 2) + 1];

  for (int it = 0; it < NI; ++it) {
    float4 nqa = qa, nqb = qb, nka = ka, nkb = kb;
    const int rn = r + 4;
    if (it + 1 < NI) {                    // prefetch next row (hides under 64 FMAs)
      nqa = Qg[rn * 16 + (q0 >> 2)];
      nqb = Qg[rn * 16 + (q0 >> 2) + 1];
      nka = Kg[rn * 16 + (k0 >> 2)];
      nkb = Kg[rn * 16 + (k0 >> 2) + 1];
    }
    float qv[8] = {qa.x, qa.y, qa.z, qa.w, qb.x, qb.y, qb.z, qb.w};
    float kv[8] = {ka.x, ka.y, ka.z, ka.w, kb.x, kb.y, kb.z, kb.w};
#pragma unroll
    for (int ii = 0; ii < 8; ++ii)
#pragma unroll
      for (int jj = 0; jj < 8; ++jj)
        acc[ii][jj] += qv[ii] * kv[jj];
    qa = nqa; qb = nqb; ka = nka; kb = nkb;
    r = rn;
  }

  // ---- cross-wave reduction: waves 2,3 publish; waves 0,1 add; halves summed on store ----
  __syncthreads();
  if (w >= 2) {
    float4* dst = (float4*)red[w - 2];
#pragma unroll
    for (int i = 0; i < 8; ++i) {
      dst[(q0 + i) * 16 + (k0 >> 2)]     = make_float4(acc[i][0], acc[i][1], acc[i][2], acc[i][3]);
      dst[(q0 + i) * 16 + (k0 >> 2) + 1] = make_float4(acc[i][4], acc[i][5], acc[i][6], acc[i][7]);
    }
  }
  __syncthreads();
  if (w < 2) {
    float4* dst = (float4*)red[w];
#pragma unroll
    for (int i = 0; i < 8; ++i) {
      float4 u = dst[(q0 + i) * 16 + (k0 >> 2)];
      float4 v = dst[(q0 + i) * 16 + (k0 >> 2) + 1];
      dst[(q0 + i) * 16 + (k0 >> 2)]     = make_float4(u.x + acc[i][0], u.y + acc[i][1], u.z + acc[i][2], u.w + acc[i][3]);
      dst[(q0 + i) * 16 + (k0 >> 2) + 1] = make_float4(v.x + acc[i][4], v.y + acc[i][5], v.z + acc[i][6], v.w + acc[i][7]);
    }
  }
  __syncthreads();
  float4* p4 = (float4*)(partial + (size_t)bs * 4096);
  const float4* r0 = (const float4*)red[0];
  const float4* r1 = (const float4*)red[1];
#pragma unroll
  for (int c = 0; c < 4; ++c) {
    float4 x = r0[c * 256 + tid];
    float4 y = r1[c * 256 + tid];
    p4[c * 256 + tid] = make_float4(x.x + y.x, x.y + y.y, x.z + y.z, x.w + y.w);
  }
}

// ---------------- Kernel B: reduce partials + softmax, store TRANSPOSED attn_t[b][k][q] ----------------
template <int SPLIT>
__global__ __launch_bounds__(64) void softmax_kernel(
    const float* __restrict__ partial, float* __restrict__ attn_t) {
  const int blk = blockIdx.x;           // b*16 + qquad
  const int b = blk >> 4;
  const int q0 = (blk & 15) * 4;
  const int l = threadIdx.x;
  const int ql = l >> 4;                // q = q0+ql
  const int k4 = l & 15;                // float4 column

  const float4* P = (const float4*)partial;
  float4 v = make_float4(0.f, 0.f, 0.f, 0.f);
  for (int s = 0; s < SPLIT; ++s) {
    float4 t = P[((size_t)(b * SPLIT + s) * 64 + q0 + ql) * 16 + k4];
    v.x += t.x; v.y += t.y; v.z += t.z; v.w += t.w;
  }

  float m = fmaxf(fmaxf(v.x, v.y), fmaxf(v.z, v.w));
#pragma unroll
  for (int off = 8; off > 0; off >>= 1)
    m = fmaxf(m, __shfl_xor(m, off, 64));
  float4 e = make_float4(__expf(v.x - m), __expf(v.y - m), __expf(v.z - m), __expf(v.w - m));
  float sum = e.x + e.y + e.z + e.w;
#pragma unroll
  for (int off = 8; off > 0; off >>= 1)
    sum += __shfl_xor(sum, off, 64);
  const float inv = 1.f / sum;

  float* A = attn_t + (size_t)b * 4096;   // [k][q]
  A[(4 * k4 + 0) * 64 + q0 + ql] = e.x * inv;
  A[(4 * k4 + 1) * 64 + q0 + ql] = e.y * inv;
  A[(4 * k4 + 2) * 64 + q0 + ql] = e.z * inv;
  A[(4 * k4 + 3) * 64 + q0 + ql] = e.w * inv;
}

// ---------------- Kernel C: out = V * attn_t; V from GLOBAL (1 wave per row), only A in LDS ----------------
// Block = 128 rows x 64 q. Thread (g=tid>>4, qg=tid&15): rows {16i+g}, cols
// {4qg..4qg+3}. V row-quads read directly from global (4 distinct 16B addrs
// per instr, 16-lane broadcast, sequential k4 -> L1-merged, HBM-exact) with
// one-k4-ahead prefetch. A (genuine cross-wave reuse) staged once in 16 KB
// LDS; reads are 16 consecutive float4 -> 2-way bank alias (free). One
// barrier total; 32 independent accumulators; coalesced float4 stores.
__global__ __launch_bounds__(256) void out_kernel(
    const float* __restrict__ V, const float* __restrict__ attn_t,
    float* __restrict__ out) {
  const int b = blockIdx.x >> 7;        // 128 tiles of 128 rows per batch
  const int tile = blockIdx.x & 127;
  const int tid = threadIdx.x;
  const int g = tid >> 4;
  const int qg = tid & 15;

  __shared__ float4 Al[64 * 16];        // attn_t[k][q] row-major, 16 KB

  const float4* Ag = (const float4*)(attn_t + (size_t)b * 4096);
#pragma unroll
  for (int u = 0; u < 4; ++u)
    Al[u * 256 + tid] = Ag[u * 256 + tid];
  __syncthreads();

  const float4* Vg = (const float4*)(V + ((size_t)b * 16384 + (size_t)tile * 128) * 64);

  float acc[8][4];
#pragma unroll
  for (int i = 0; i < 8; ++i)
#pragma unroll
    for (int j = 0; j < 4; ++j) acc[i][j] = 0.f;

  float4 vc[8];
#pragma unroll
  for (int i = 0; i < 8; ++i) vc[i] = Vg[(i * 16 + g) * 16];

  for (int k4 = 0; k4 < 16; ++k4) {
    float4 vn[8];
    if (k4 < 15) {
#pragma unroll
      for (int i = 0; i < 8; ++i) vn[i] = Vg[(i * 16 + g) * 16 + k4 + 1];
    }
    const float4 a0 = Al[(4 * k4 + 0) * 16 + qg];
    const float4 a1 = Al[(4 * k4 + 1) * 16 + qg];
    const float4 a2 = Al[(4 * k4 + 2) * 16 + qg];
    const float4 a3 = Al[(4 * k4 + 3) * 16 + qg];
#pragma unroll
    for (int i = 0; i < 8; ++i) {
      const float4 v = vc[i];
      acc[i][0] += v.x * a0.x + v.y * a1.x + v.z * a2.x + v.w * a3.x;
      acc[i][1] += v.x * a0.y + v.y * a1.y + v.z * a2.y + v.w * a3.y;
      acc[i][2] += v.x * a0.z + v.y * a1.z + v.z * a2.z + v.w * a3.z;
      acc[i][3] += v.x * a0.w + v.y * a1.w + v.z * a2.w + v.w * a3.w;
    }
    if (k4 < 15) {
#pragma unroll
      for (int i = 0; i < 8; ++i) vc[i] = vn[i];
    }
  }

  float4* og = (float4*)(out + ((size_t)b * 16384 + (size_t)tile * 128) * 64);
#pragma unroll
  for (int i = 0; i < 8; ++i) {
    const int row = i * 16 + g;
    og[row * 16 + qg] = make_float4(acc[i][0], acc[i][1], acc[i][2], acc[i][3]);
  }
}

extern "C" void kernel_launch(void* const* d_in, const int* in_sizes, int n_in,
                              void* d_out, int out_size, void* d_ws, size_t ws_size,
                              hipStream_t stream) {
  const float* Q = (const float*)d_in[0];
  const float* K = (const float*)d_in[1];
  const float* V = (const float*)d_in[2];
  float* out = (float*)d_out;

  const size_t need64 = (size_t)16 * 64 * 4096 * 4 + (size_t)16 * 4096 * 4;  // 16 MiB + 256 KiB

  if (ws_size >= need64) {
    float* partial = (float*)d_ws;
    float* attn_t = partial + (size_t)16 * 64 * 4096;
    scores_kernel<64><<<16 * 64, 256, 0, stream>>>(Q, K, partial);
    softmax_kernel<64><<<16 * 16, 64, 0, stream>>>(partial, attn_t);
    out_kernel<<<16 * 128, 256, 0, stream>>>(V, attn_t, out);
  } else {
    float* partial = (float*)d_ws;
    float* attn_t = partial + (size_t)16 * 32 * 4096;
    scores_kernel<32><<<16 * 32, 256, 0, stream>>>(Q, K, partial);
    softmax_kernel<32><<<16 * 16, 64, 0, stream>>>(partial, attn_t);
    out_kernel<<<16 * 128, 256, 0, stream>>>(V, attn_t, out);
  }
}

// Round 5
// 234.465 us; speedup vs baseline: 1.6231x; 1.1351x over previous
//
#include <hip/hip_runtime.h>

// Attention over channel dim: B=16, HW=16384, C=64, fp32.
// scores[b,q,k] = sum_hw Q[b,hw,q]*K[b,hw,k]; attn=softmax_k; out[b,hw,q]=sum_k attn[b,q,k]*V[b,hw,k]
//
// ws: partial scores [B][SPLIT][64][64] fp32, then attn_t [B][64k][64q] fp32 (256 KB).
// SPLIT=64 (16 MiB) if ws allows, else 32 (8 MiB).
//
// Round-5 config: round-1 proven structures (LDS-staged scores, LDS V+A out)
// with SPLIT=64 for scores occupancy and a 4-wave softmax.

#define TILE_ROWS 32

// ---------------- Kernel A: partial scores (split-K GEMM, 8x8 register tile, double-buffered) ----------------
// PROVEN structure (round 1: 59.5 us @ SPLIT=32). 4 waves compute the SAME
// 64x64 (q,k) tile over DISJOINT row subsets (r = i*4 + w). T14 staging:
// issue next tile's global loads, compute, LDS-write, ONE barrier per iter.
// SPLIT=64 -> 1024 blocks -> 4 blocks/CU: overlaps per-block barrier drains.
template <int SPLIT>
__global__ __launch_bounds__(256) void scores_kernel(
    const float* __restrict__ Q, const float* __restrict__ K,
    float* __restrict__ partial) {
  constexpr int CH = 16384 / SPLIT;       // rows per split chunk
  constexpr int NT = CH / TILE_ROWS;      // tile iterations
  const int bs = blockIdx.x;              // b * SPLIT + s
  const int b = bs / SPLIT;
  const int s = bs % SPLIT;
  const int tid = threadIdx.x;
  const int w = tid >> 6;                 // wave 0..3
  const int l = tid & 63;
  const int q0 = (l >> 3) * 8;            // 8 q per lane
  const int k0 = (l & 7) * 8;             // 8 k per lane

  __shared__ union {
    struct { float4 q[2][512]; float4 k[2][512]; } t;  // 32 KB double-buffered tiles
    float red[2][4096];                                // 32 KB cross-wave reduction
  } lds;

  float acc[8][8];
#pragma unroll
  for (int i = 0; i < 8; ++i)
#pragma unroll
    for (int j = 0; j < 8; ++j) acc[i][j] = 0.f;

  const float4* Qg = (const float4*)(Q + ((size_t)b * 16384 + (size_t)s * CH) * 64);
  const float4* Kg = (const float4*)(K + ((size_t)b * 16384 + (size_t)s * CH) * 64);

  // prologue: stage tile 0 into buffer 0
  lds.t.q[0][tid]       = Qg[tid];
  lds.t.q[0][tid + 256] = Qg[tid + 256];
  lds.t.k[0][tid]       = Kg[tid];
  lds.t.k[0][tid + 256] = Kg[tid + 256];

  for (int t = 0; t < NT; ++t) {
    __syncthreads();                    // buf (t&1) ready; buf ((t+1)&1) free
    const int cb = t & 1;

    float4 pq0, pq1, pk0, pk1;
    if (t + 1 < NT) {
      pq0 = Qg[(t + 1) * 512 + tid];
      pq1 = Qg[(t + 1) * 512 + tid + 256];
      pk0 = Kg[(t + 1) * 512 + tid];
      pk1 = Kg[(t + 1) * 512 + tid + 256];
    }

#pragma unroll
    for (int i = 0; i < 8; ++i) {
      const int r = (i << 2) + w;       // wave w handles rows w,4+w,...,28+w
      float4 qa = lds.t.q[cb][r * 16 + (q0 >> 2)];
      float4 qb = lds.t.q[cb][r * 16 + (q0 >> 2) + 1];
      float4 ka = lds.t.k[cb][r * 16 + (k0 >> 2)];
      float4 kb = lds.t.k[cb][r * 16 + (k0 >> 2) + 1];
      float qv[8] = {qa.x, qa.y, qa.z, qa.w, qb.x, qb.y, qb.z, qb.w};
      float kv[8] = {ka.x, ka.y, ka.z, ka.w, kb.x, kb.y, kb.z, kb.w};
#pragma unroll
      for (int ii = 0; ii < 8; ++ii)
#pragma unroll
        for (int jj = 0; jj < 8; ++jj)
          acc[ii][jj] += qv[ii] * kv[jj];
    }

    if (t + 1 < NT) {
      const int nb = (t + 1) & 1;
      lds.t.q[nb][tid]       = pq0;
      lds.t.q[nb][tid + 256] = pq1;
      lds.t.k[nb][tid]       = pk0;
      lds.t.k[nb][tid + 256] = pk1;
    }
  }

  // ---- cross-wave reduction: waves 2,3 publish; waves 0,1 add; halves summed on store ----
  __syncthreads();
  if (w >= 2) {
    float4* dst = (float4*)lds.red[w - 2];
#pragma unroll
    for (int i = 0; i < 8; ++i) {
      dst[(q0 + i) * 16 + (k0 >> 2)]     = make_float4(acc[i][0], acc[i][1], acc[i][2], acc[i][3]);
      dst[(q0 + i) * 16 + (k0 >> 2) + 1] = make_float4(acc[i][4], acc[i][5], acc[i][6], acc[i][7]);
    }
  }
  __syncthreads();
  if (w < 2) {
    float4* dst = (float4*)lds.red[w];
#pragma unroll
    for (int i = 0; i < 8; ++i) {
      float4 u = dst[(q0 + i) * 16 + (k0 >> 2)];
      float4 v = dst[(q0 + i) * 16 + (k0 >> 2) + 1];
      dst[(q0 + i) * 16 + (k0 >> 2)]     = make_float4(u.x + acc[i][0], u.y + acc[i][1], u.z + acc[i][2], u.w + acc[i][3]);
      dst[(q0 + i) * 16 + (k0 >> 2) + 1] = make_float4(v.x + acc[i][4], v.y + acc[i][5], v.z + acc[i][6], v.w + acc[i][7]);
    }
  }
  __syncthreads();
  float4* p4 = (float4*)(partial + (size_t)bs * 4096);
  const float4* r0 = (const float4*)lds.red[0];
  const float4* r1 = (const float4*)lds.red[1];
#pragma unroll
  for (int c = 0; c < 4; ++c) {
    float4 x = r0[c * 256 + tid];
    float4 y = r1[c * 256 + tid];
    p4[c * 256 + tid] = make_float4(x.x + y.x, x.y + y.y, x.z + y.z, x.w + y.w);
  }
}

// ---------------- Kernel B: reduce partials + softmax, store TRANSPOSED attn_t[b][k][q] ----------------
// Block = (b, q-quad), 4 waves: wave w sums splits {w, w+4, ...}; 4-way LDS
// combine; wave 0 does the 16-lane shuffle softmax + transposed store.
template <int SPLIT>
__global__ __launch_bounds__(256) void softmax_kernel(
    const float* __restrict__ partial, float* __restrict__ attn_t) {
  const int blk = blockIdx.x;           // b*16 + qquad
  const int b = blk >> 4;
  const int q0 = (blk & 15) * 4;
  const int tid = threadIdx.x;
  const int w = tid >> 6;
  const int l = tid & 63;
  const int ql = l >> 4;                // q = q0+ql
  const int k4 = l & 15;                // float4 column

  __shared__ float4 red4[4][64];        // 4 KB

  const float4* P = (const float4*)partial;
  float4 v = make_float4(0.f, 0.f, 0.f, 0.f);
  for (int s = w; s < SPLIT; s += 4) {
    float4 t = P[((size_t)(b * SPLIT + s) * 64 + q0 + ql) * 16 + k4];
    v.x += t.x; v.y += t.y; v.z += t.z; v.w += t.w;
  }
  red4[w][l] = v;
  __syncthreads();
  if (w != 0) return;

  float4 v1 = red4[1][l], v2 = red4[2][l], v3 = red4[3][l];
  v.x += v1.x + v2.x + v3.x;
  v.y += v1.y + v2.y + v3.y;
  v.z += v1.z + v2.z + v3.z;
  v.w += v1.w + v2.w + v3.w;

  float m = fmaxf(fmaxf(v.x, v.y), fmaxf(v.z, v.w));
#pragma unroll
  for (int off = 8; off > 0; off >>= 1)
    m = fmaxf(m, __shfl_xor(m, off, 64));   // reduce across the 16 lanes sharing q
  float4 e = make_float4(__expf(v.x - m), __expf(v.y - m), __expf(v.z - m), __expf(v.w - m));
  float sum = e.x + e.y + e.z + e.w;
#pragma unroll
  for (int off = 8; off > 0; off >>= 1)
    sum += __shfl_xor(sum, off, 64);
  const float inv = 1.f / sum;

  float* A = attn_t + (size_t)b * 4096;   // [k][q]
  A[(4 * k4 + 0) * 64 + q0 + ql] = e.x * inv;
  A[(4 * k4 + 1) * 64 + q0 + ql] = e.y * inv;
  A[(4 * k4 + 2) * 64 + q0 + ql] = e.z * inv;
  A[(4 * k4 + 3) * 64 + q0 + ql] = e.w * inv;
}

// ---------------- Kernel C: out = V * attn_t (register-tiled GEMM, 8x4 per thread) ----------------
// PROVEN round-1 structure (<=58 us, 0 bank conflicts). Block = 128 rows x
// 64 q; thread (g=tid>>4, qg=tid&15) computes rows {16i+g} x cols
// {4qg..4qg+3}. V in LDS padded to 68 floats/row (banks 4g+4k4:
// conflict-free); attn_t float4 over q (2-way alias, free). 12 ds_read_b128
// per 128 FMA-instrs, 32 independent accumulators, coalesced float4 stores.
__global__ __launch_bounds__(256) void out_kernel(
    const float* __restrict__ V, const float* __restrict__ attn_t,
    float* __restrict__ out) {
  const int b = blockIdx.x >> 7;        // 128 tiles of 128 rows per batch
  const int tile = blockIdx.x & 127;
  const int tid = threadIdx.x;
  const int g = tid >> 4;               // row group 0..15
  const int qg = tid & 15;              // q group 0..15

  __shared__ float4 Vl[128 * 17];       // row r at float4 index r*17 (68-float pad)  34 KB
  __shared__ float4 Al[64 * 16];        // attn_t[k][q] row-major, no pad             16 KB

  const float4* Vg = (const float4*)(V + ((size_t)b * 16384 + (size_t)tile * 128) * 64);
#pragma unroll
  for (int u = 0; u < 8; ++u) {
    const int idx = u * 256 + tid;      // 0..2047 float4 of the 128x64 tile
    Vl[(idx >> 4) * 17 + (idx & 15)] = Vg[idx];
  }
  const float4* Ag = (const float4*)(attn_t + (size_t)b * 4096);
#pragma unroll
  for (int u = 0; u < 4; ++u)
    Al[u * 256 + tid] = Ag[u * 256 + tid];
  __syncthreads();

  float acc[8][4];
#pragma unroll
  for (int i = 0; i < 8; ++i)
#pragma unroll
    for (int j = 0; j < 4; ++j) acc[i][j] = 0.f;

  for (int k4 = 0; k4 < 16; ++k4) {
    const float4 a0 = Al[(4 * k4 + 0) * 16 + qg];   // attn[q0..q0+3][4k4+0]
    const float4 a1 = Al[(4 * k4 + 1) * 16 + qg];
    const float4 a2 = Al[(4 * k4 + 2) * 16 + qg];
    const float4 a3 = Al[(4 * k4 + 3) * 16 + qg];
#pragma unroll
    for (int i = 0; i < 8; ++i) {
      const float4 v = Vl[(i * 16 + g) * 17 + k4];  // V[row][4k4..4k4+3]
      acc[i][0] += v.x * a0.x + v.y * a1.x + v.z * a2.x + v.w * a3.x;
      acc[i][1] += v.x * a0.y + v.y * a1.y + v.z * a2.y + v.w * a3.y;
      acc[i][2] += v.x * a0.z + v.y * a1.z + v.z * a2.z + v.w * a3.z;
      acc[i][3] += v.x * a0.w + v.y * a1.w + v.z * a2.w + v.w * a3.w;
    }
  }

  float4* og = (float4*)(out + ((size_t)b * 16384 + (size_t)tile * 128) * 64);
#pragma unroll
  for (int i = 0; i < 8; ++i) {
    const int row = i * 16 + g;
    og[row * 16 + qg] = make_float4(acc[i][0], acc[i][1], acc[i][2], acc[i][3]);
  }
}

extern "C" void kernel_launch(void* const* d_in, const int* in_sizes, int n_in,
                              void* d_out, int out_size, void* d_ws, size_t ws_size,
                              hipStream_t stream) {
  const float* Q = (const float*)d_in[0];
  const float* K = (const float*)d_in[1];
  const float* V = (const float*)d_in[2];
  float* out = (float*)d_out;

  const size_t need64 = (size_t)16 * 64 * 4096 * 4 + (size_t)16 * 4096 * 4;  // 16 MiB + 256 KiB

  if (ws_size >= need64) {
    float* partial = (float*)d_ws;
    float* attn_t = partial + (size_t)16 * 64 * 4096;
    scores_kernel<64><<<16 * 64, 256, 0, stream>>>(Q, K, partial);
    softmax_kernel<64><<<16 * 16, 256, 0, stream>>>(partial, attn_t);
    out_kernel<<<16 * 128, 256, 0, stream>>>(V, attn_t, out);
  } else {
    float* partial = (float*)d_ws;
    float* attn_t = partial + (size_t)16 * 32 * 4096;
    scores_kernel<32><<<16 * 32, 256, 0, stream>>>(Q, K, partial);
    softmax_kernel<32><<<16 * 16, 256, 0, stream>>>(partial, attn_t);
    out_kernel<<<16 * 128, 256, 0, stream>>>(V, attn_t, out);
  }
}